// Round 2
// baseline (35183.969 us; speedup 1.0000x reference)
//
#include <hip/hip_runtime.h>
#include <math.h>

#define B_  32
#define T_  512
#define I_  128
#define H_  512
#define G4_ 2048   // 4*H

// ---------------------------------------------------------------------------
// Tiled fp32 GEMM: C[m][n] = sum_k A[m][k] * Bm[n][k]  (+ bias[n] if bias)
// 64x64 tile, K=128 staged in two 64-halves, LDS transposed with pad 65.
// ---------------------------------------------------------------------------
__global__ __launch_bounds__(256) void gemm_abt(
    const float* __restrict__ A, const float* __restrict__ Bm, float* __restrict__ C,
    const float* __restrict__ bias, long sA, long sB, long sC, int ldc)
{
  __shared__ float Al[64][65];
  __shared__ float Bl[64][65];
  const long z = blockIdx.z;
  A += z * sA; Bm += z * sB; C += z * sC;
  const int m0 = blockIdx.x * 64, n0 = blockIdx.y * 64;
  const int tid = threadIdx.x;
  const int tx = tid & 15, ty = tid >> 4;
  float acc[4][4] = {};

  for (int h = 0; h < 2; ++h) {
    const int k0 = h * 64;
    __syncthreads();
    #pragma unroll
    for (int s = 0; s < 4; ++s) {
      int idx = tid + s * 256;          // 0..1023
      int m  = idx >> 4;                // 0..63
      int k4 = (idx & 15) << 2;         // 0..60
      float4 a4 = *(const float4*)&A[(long)(m0 + m) * 128 + k0 + k4];
      Al[k4 + 0][m] = a4.x; Al[k4 + 1][m] = a4.y; Al[k4 + 2][m] = a4.z; Al[k4 + 3][m] = a4.w;
      float4 b4 = *(const float4*)&Bm[(long)(n0 + m) * 128 + k0 + k4];
      Bl[k4 + 0][m] = b4.x; Bl[k4 + 1][m] = b4.y; Bl[k4 + 2][m] = b4.z; Bl[k4 + 3][m] = b4.w;
    }
    __syncthreads();
    #pragma unroll 8
    for (int k = 0; k < 64; ++k) {
      float a0 = Al[k][ty*4+0], a1 = Al[k][ty*4+1], a2 = Al[k][ty*4+2], a3 = Al[k][ty*4+3];
      float b0 = Bl[k][tx*4+0], b1 = Bl[k][tx*4+1], b2 = Bl[k][tx*4+2], b3 = Bl[k][tx*4+3];
      acc[0][0] += a0*b0; acc[0][1] += a0*b1; acc[0][2] += a0*b2; acc[0][3] += a0*b3;
      acc[1][0] += a1*b0; acc[1][1] += a1*b1; acc[1][2] += a1*b2; acc[1][3] += a1*b3;
      acc[2][0] += a2*b0; acc[2][1] += a2*b1; acc[2][2] += a2*b2; acc[2][3] += a2*b3;
      acc[3][0] += a3*b0; acc[3][1] += a3*b1; acc[3][2] += a3*b2; acc[3][3] += a3*b3;
    }
  }
  #pragma unroll
  for (int i = 0; i < 4; ++i) {
    #pragma unroll
    for (int j = 0; j < 4; ++j) {
      float bb = bias ? bias[n0 + tx*4 + j] : 0.f;
      C[(long)(m0 + ty*4 + i) * ldc + n0 + tx*4 + j] = acc[i][j] + bb;
    }
  }
}

// ---------------------------------------------------------------------------
// Inclusive cumsum of Deltas over T per batch (Hillis-Steele in LDS).
// ---------------------------------------------------------------------------
__global__ __launch_bounds__(512) void cumsum_k(const float* __restrict__ Deltas,
                                                float* __restrict__ dcum)
{
  __shared__ float s[512];
  const int b = blockIdx.x, t = threadIdx.x;
  s[t] = Deltas[b * 512 + t];
  __syncthreads();
  for (int off = 1; off < 512; off <<= 1) {
    float v = (t >= off) ? s[t - off] : 0.f;
    __syncthreads();
    s[t] += v;
    __syncthreads();
  }
  dcum[b * 512 + t] = s[t];
}

// ---------------------------------------------------------------------------
// In-place per-row masked softmax * 1/log(e + D) weight. Row (b,t), 1 wave.
// ---------------------------------------------------------------------------
__global__ __launch_bounds__(64) void softmax_k(float* __restrict__ a,
                                                const float* __restrict__ dcum)
{
  const int t = blockIdx.x, b = blockIdx.y;
  float* row = a + ((long)b * T_ + t) * T_;
  const int lane = threadIdx.x;
  if (t == 0) {
    #pragma unroll
    for (int i = 0; i < 8; ++i) row[i * 64 + lane] = 0.f;
    return;
  }
  float vals[8];
  float mx = -3.4e38f;
  #pragma unroll
  for (int i = 0; i < 8; ++i) {
    int j = i * 64 + lane;
    float v = (j < t) ? row[j] : -3.4e38f;
    vals[i] = v; mx = fmaxf(mx, v);
  }
  #pragma unroll
  for (int off = 1; off < 64; off <<= 1) mx = fmaxf(mx, __shfl_xor(mx, off));
  float sum = 0.f;
  #pragma unroll
  for (int i = 0; i < 8; ++i) {
    int j = i * 64 + lane;
    float e = (j < t) ? expf(vals[i] - mx) : 0.f;
    vals[i] = e; sum += e;
  }
  #pragma unroll
  for (int off = 1; off < 64; off <<= 1) sum += __shfl_xor(sum, off);
  const float E = 2.718281828459045f;
  const float dct = dcum[b * 512 + t];
  const float inv = 1.f / sum;
  #pragma unroll
  for (int i = 0; i < 8; ++i) {
    int j = i * 64 + lane;
    float w = (j < t) ? 1.f / logf(E + dct - dcum[b * 512 + j]) : 0.f;
    row[j] = vals[i] * inv * w;
  }
}

// ---------------------------------------------------------------------------
// Grid barrier: sense via monotonically increasing gen counter. Returns 1 on
// abort (spin cap exceeded anywhere -> everyone unwinds quickly).
// bar[0]=cnt, bar[1]=gen, bar[2]=abort
// ---------------------------------------------------------------------------
__device__ __forceinline__ int barrier_sync(unsigned* bar, unsigned nblk)
{
  __shared__ int s_ab;
  __syncthreads();
  if (threadIdx.x == 0) {
    int ab = (int)__hip_atomic_load(&bar[2], __ATOMIC_RELAXED, __HIP_MEMORY_SCOPE_AGENT);
    if (!ab) {
      __threadfence();   // release prior writes to device scope
      unsigned target = __hip_atomic_load(&bar[1], __ATOMIC_RELAXED, __HIP_MEMORY_SCOPE_AGENT) + 1u;
      unsigned old = __hip_atomic_fetch_add(&bar[0], 1u, __ATOMIC_ACQ_REL, __HIP_MEMORY_SCOPE_AGENT);
      if (old == nblk - 1u) {
        __hip_atomic_store(&bar[0], 0u, __ATOMIC_RELAXED, __HIP_MEMORY_SCOPE_AGENT);
        __hip_atomic_fetch_add(&bar[1], 1u, __ATOMIC_RELEASE, __HIP_MEMORY_SCOPE_AGENT);
      } else {
        long spins = 0;
        for (;;) {
          unsigned gv = __hip_atomic_load(&bar[1], __ATOMIC_RELAXED, __HIP_MEMORY_SCOPE_AGENT);
          if ((int)(gv - target) >= 0) break;
          if (((++spins) & 1023) == 0) {
            if (__hip_atomic_load(&bar[2], __ATOMIC_RELAXED, __HIP_MEMORY_SCOPE_AGENT)) { ab = 1; break; }
            if (spins > 20L * 1000 * 1000) {
              __hip_atomic_store(&bar[2], 1u, __ATOMIC_RELAXED, __HIP_MEMORY_SCOPE_AGENT);
              ab = 1; break;
            }
          }
          __builtin_amdgcn_s_sleep(2);
        }
        __threadfence();  // acquire side
      }
    }
    s_ab = ab;
  }
  __syncthreads();
  return s_ab;
}

// ---------------------------------------------------------------------------
// Persistent recurrent kernel. 256 blocks x 256 threads, 1 block/CU.
// G-role (block g): rs=g&63 -> gate rows [rs*32, rs*32+32), bg=g>>6 ->
//   batches [bg*8, bg*8+8). Weights stationary in VGPRs (80 floats/thread,
//   column-interleaved c = cg*4 + k*32 over the concat [v(128) | h(512)]).
// U-role (block g): b_u=g>>3, hs=g&7 -> h slice [hs*64, hs*64+64) of batch
//   b_u; c_n history [512][64] lives in LDS for the attention-weighted C.
// ---------------------------------------------------------------------------
__global__ __launch_bounds__(256, 1) void recurrent_k(
    const float* __restrict__ v_buf,   // [B][T][I]
    const float* __restrict__ alpha,   // [B][T][T] (softmax*w, 0 where j>=t)
    const float* __restrict__ W_ih,    // [4H][I]
    const float* __restrict__ W_hh,    // [4H][H]
    const float* __restrict__ b_ih, const float* __restrict__ b_hh,
    float* __restrict__ gates,         // [B][4H] scratch
    float* __restrict__ out,           // [B][T][H] = h_n (also h state)
    unsigned* bar)
{
  extern __shared__ float lds[];
  float* hv   = lds;                   // [8][640]  staged [v | h_prev]
  float* cn   = lds + 8 * 640;         // [512][64] cell history
  float* red  = cn + 512 * 64;         // [4][64]
  float* gred = red + 256;             // [4][64]

  const int tid = threadIdx.x;
  const int g = blockIdx.x;
  const int rs = g & 63, bg = g >> 6;       // G role
  const int b_u = g >> 3, hs = g & 7;       // U role
  const int r_l = tid >> 3, cg = tid & 7;   // G thread: row-local, col group
  const int row = rs * 32 + r_l;
  const int jg = tid >> 6, l = tid & 63;    // U thread

  // stationary weights: cols c = cg*4 + k*32 of [W_ih | W_hh] row
  float4 wreg[20];
  #pragma unroll
  for (int k = 0; k < 20; ++k) {
    int c0 = cg * 4 + k * 32;
    if (k < 4) wreg[k] = *(const float4*)&W_ih[(long)row * I_ + c0];
    else       wreg[k] = *(const float4*)&W_hh[(long)row * H_ + (c0 - 128)];
  }
  const float bias = b_ih[row] + b_hh[row];

  for (int t = 0; t < T_; ++t) {
    // ---- stage hv = [v(b,t,:) | h(b,t-1,:)] for the 8 G-batches ----
    #pragma unroll
    for (int s = 0; s < 5; ++s) {
      int f4i = tid + s * 256;              // 0..1279
      int bp  = f4i / 160;                  // 160 float4 per batch row
      int c4  = (f4i - bp * 160) * 4;
      float4 val;
      if (c4 < 128) {
        val = *(const float4*)&v_buf[(((long)(bg * 8 + bp)) * T_ + t) * I_ + c4];
      } else if (t == 0) {
        val = make_float4(0.f, 0.f, 0.f, 0.f);
      } else {
        val = *(const float4*)&out[(((long)(bg * 8 + bp)) * T_ + (t - 1)) * H_ + (c4 - 128)];
      }
      *(float4*)&hv[bp * 640 + c4] = val;
    }
    __syncthreads();

    // ---- G: gates[b, row] partial dot over this cg's 80 columns ----
    float acc[8] = {};
    #pragma unroll
    for (int k = 0; k < 20; ++k) {
      float4 w4 = wreg[k];
      #pragma unroll
      for (int bp = 0; bp < 8; ++bp) {
        float4 x = *(const float4*)&hv[bp * 640 + cg * 4 + k * 32];
        acc[bp] += w4.x * x.x + w4.y * x.y + w4.z * x.z + w4.w * x.w;
      }
    }
    #pragma unroll
    for (int off = 1; off < 8; off <<= 1) {
      #pragma unroll
      for (int bp = 0; bp < 8; ++bp) acc[bp] += __shfl_xor(acc[bp], off);
    }
    if (cg == 0) {
      #pragma unroll
      for (int bp = 0; bp < 8; ++bp)
        gates[(long)(bg * 8 + bp) * G4_ + row] = acc[bp] + bias;
    }
    if (barrier_sync(bar, 256)) return;

    // ---- U: C = sum_j alpha[b,t,j] * c_n[j], LSTM update ----
    gred[tid] = gates[(long)b_u * G4_ + jg * H_ + hs * 64 + l];  // jg = gate type
    float partial = 0.f;
    const float* arow = alpha + ((long)b_u * T_ + t) * T_;
    int j0 = jg * 128;
    int j1 = j0 + 128; if (j1 > t) j1 = t;
    #pragma unroll 4
    for (int j = j0; j < j1; ++j)
      partial += arow[j] * cn[j * 64 + l];
    red[tid] = partial;
    __syncthreads();
    if (tid < 64) {
      float C  = red[l] + red[64 + l] + red[128 + l] + red[192 + l];
      float gi = gred[l], gf = gred[64 + l], gg = gred[128 + l], go = gred[192 + l];
      float si = 1.f / (1.f + expf(-gi));
      float sf = 1.f / (1.f + expf(-gf));
      float so = 1.f / (1.f + expf(-go));
      float cnew = sf * C + si * tanhf(gg);
      float hnew = so * tanhf(cnew);
      out[((long)b_u * T_ + t) * H_ + hs * 64 + l] = hnew;
      cn[t * 64 + l] = cnew;
    }
    if (barrier_sync(bar, 256)) return;
  }
}

// ---------------------------------------------------------------------------
extern "C" void kernel_launch(void* const* d_in, const int* in_sizes, int n_in,
                              void* d_out, int out_size, void* d_ws, size_t ws_size,
                              hipStream_t stream)
{
  const float* values  = (const float*)d_in[0];
  const float* Deltas  = (const float*)d_in[1];
  // d_in[2] = ys (unused by the reference computation)
  const float* W_ih    = (const float*)d_in[3];
  const float* W_hh    = (const float*)d_in[4];
  const float* b_ih    = (const float*)d_in[5];
  const float* b_hh    = (const float*)d_in[6];
  const float* atten_W = (const float*)d_in[7];
  const float* atten_b = (const float*)d_in[8];
  float* out = (float*)d_out;

  char* ws = (char*)d_ws;
  unsigned* bar = (unsigned*)ws;                       // 64 B
  float* v_buf  = (float*)(ws + 256);                  // 8 MB   [B][T][I]
  float* a_buf  = (float*)(ws + 256 + 8388608);        // 32 MB  [B][T][T]
  float* dcum   = (float*)(ws + 256 + 8388608 + 33554432);            // 64 KB
  float* gates  = (float*)(ws + 256 + 8388608 + 33554432 + 65536);    // 256 KB

  hipMemsetAsync(bar, 0, 64, stream);

  // v = values @ atten_W^T + atten_b   (M=B*T=16384, N=128, K=128)
  gemm_abt<<<dim3(256, 2, 1), 256, 0, stream>>>(values, atten_W, v_buf, atten_b,
                                                0, 0, 0, 128);
  cumsum_k<<<32, 512, 0, stream>>>(Deltas, dcum);
  // a[b,t,j] = v[b,t,:] . values[b,j,:]   (per-batch 512x512x128)
  gemm_abt<<<dim3(8, 8, 32), 256, 0, stream>>>(v_buf, values, a_buf, nullptr,
                                               512L * 128, 512L * 128, 512L * 512, 512);
  softmax_k<<<dim3(512, 32), 64, 0, stream>>>(a_buf, dcum);

  (void)hipFuncSetAttribute((const void*)recurrent_k,
                            hipFuncAttributeMaxDynamicSharedMemorySize, 153600);
  recurrent_k<<<256, 256, 153600, stream>>>(v_buf, a_buf, W_ih, W_hh, b_ih, b_hh,
                                            gates, out, bar);
}

// Round 4
// 16601.677 us; speedup vs baseline: 2.1193x; 2.1193x over previous
//
#include <hip/hip_runtime.h>
#include <math.h>

#define B_  32
#define T_  512
#define I_  128
#define H_  512
#define G4_ 2048   // 4*H
#define GB_ 64     // blocks per sync group (dependency-closed)
#define NG_ 4      // number of groups

// ---------------------------------------------------------------------------
// Tiled fp32 GEMM: C[m][n] = sum_k A[m][k] * Bm[n][k]  (+ bias[n] if bias)
// ---------------------------------------------------------------------------
__global__ __launch_bounds__(256) void gemm_abt(
    const float* __restrict__ A, const float* __restrict__ Bm, float* __restrict__ C,
    const float* __restrict__ bias, long sA, long sB, long sC, int ldc)
{
  __shared__ float Al[64][65];
  __shared__ float Bl[64][65];
  const long z = blockIdx.z;
  A += z * sA; Bm += z * sB; C += z * sC;
  const int m0 = blockIdx.x * 64, n0 = blockIdx.y * 64;
  const int tid = threadIdx.x;
  const int tx = tid & 15, ty = tid >> 4;
  float acc[4][4] = {};

  for (int h = 0; h < 2; ++h) {
    const int k0 = h * 64;
    __syncthreads();
    #pragma unroll
    for (int s = 0; s < 4; ++s) {
      int idx = tid + s * 256;
      int m  = idx >> 4;
      int k4 = (idx & 15) << 2;
      float4 a4 = *(const float4*)&A[(long)(m0 + m) * 128 + k0 + k4];
      Al[k4 + 0][m] = a4.x; Al[k4 + 1][m] = a4.y; Al[k4 + 2][m] = a4.z; Al[k4 + 3][m] = a4.w;
      float4 b4 = *(const float4*)&Bm[(long)(n0 + m) * 128 + k0 + k4];
      Bl[k4 + 0][m] = b4.x; Bl[k4 + 1][m] = b4.y; Bl[k4 + 2][m] = b4.z; Bl[k4 + 3][m] = b4.w;
    }
    __syncthreads();
    #pragma unroll 8
    for (int k = 0; k < 64; ++k) {
      float a0 = Al[k][ty*4+0], a1 = Al[k][ty*4+1], a2 = Al[k][ty*4+2], a3 = Al[k][ty*4+3];
      float b0 = Bl[k][tx*4+0], b1 = Bl[k][tx*4+1], b2 = Bl[k][tx*4+2], b3 = Bl[k][tx*4+3];
      acc[0][0] += a0*b0; acc[0][1] += a0*b1; acc[0][2] += a0*b2; acc[0][3] += a0*b3;
      acc[1][0] += a1*b0; acc[1][1] += a1*b1; acc[1][2] += a1*b2; acc[1][3] += a1*b3;
      acc[2][0] += a2*b0; acc[2][1] += a2*b1; acc[2][2] += a2*b2; acc[2][3] += a2*b3;
      acc[3][0] += a3*b0; acc[3][1] += a3*b1; acc[3][2] += a3*b2; acc[3][3] += a3*b3;
    }
  }
  #pragma unroll
  for (int i = 0; i < 4; ++i) {
    #pragma unroll
    for (int j = 0; j < 4; ++j) {
      float bb = bias ? bias[n0 + tx*4 + j] : 0.f;
      C[(long)(m0 + ty*4 + i) * ldc + n0 + tx*4 + j] = acc[i][j] + bb;
    }
  }
}

// ---------------------------------------------------------------------------
__global__ __launch_bounds__(512) void cumsum_k(const float* __restrict__ Deltas,
                                                float* __restrict__ dcum)
{
  __shared__ float s[512];
  const int b = blockIdx.x, t = threadIdx.x;
  s[t] = Deltas[b * 512 + t];
  __syncthreads();
  for (int off = 1; off < 512; off <<= 1) {
    float v = (t >= off) ? s[t - off] : 0.f;
    __syncthreads();
    s[t] += v;
    __syncthreads();
  }
  dcum[b * 512 + t] = s[t];
}

// ---------------------------------------------------------------------------
__global__ __launch_bounds__(64) void softmax_k(float* __restrict__ a,
                                                const float* __restrict__ dcum)
{
  const int t = blockIdx.x, b = blockIdx.y;
  float* row = a + ((long)b * T_ + t) * T_;
  const int lane = threadIdx.x;
  if (t == 0) {
    #pragma unroll
    for (int i = 0; i < 8; ++i) row[i * 64 + lane] = 0.f;
    return;
  }
  float vals[8];
  float mx = -3.4e38f;
  #pragma unroll
  for (int i = 0; i < 8; ++i) {
    int j = i * 64 + lane;
    float v = (j < t) ? row[j] : -3.4e38f;
    vals[i] = v; mx = fmaxf(mx, v);
  }
  #pragma unroll
  for (int off = 1; off < 64; off <<= 1) mx = fmaxf(mx, __shfl_xor(mx, off));
  float sum = 0.f;
  #pragma unroll
  for (int i = 0; i < 8; ++i) {
    int j = i * 64 + lane;
    float e = (j < t) ? expf(vals[i] - mx) : 0.f;
    vals[i] = e; sum += e;
  }
  #pragma unroll
  for (int off = 1; off < 64; off <<= 1) sum += __shfl_xor(sum, off);
  const float E = 2.718281828459045f;
  const float dct = dcum[b * 512 + t];
  const float inv = 1.f / sum;
  #pragma unroll
  for (int i = 0; i < 8; ++i) {
    int j = i * 64 + lane;
    float w = (j < t) ? 1.f / logf(E + dct - dcum[b * 512 + j]) : 0.f;
    row[j] = vals[i] * inv * w;
  }
}

// ---------------------------------------------------------------------------
// Coherent (write-through, agent-scope) data access: no cache-flush fences.
// ---------------------------------------------------------------------------
__device__ __forceinline__ void st_wt(float* p, float v) {
  __hip_atomic_store(p, v, __ATOMIC_RELAXED, __HIP_MEMORY_SCOPE_AGENT);
}
__device__ __forceinline__ float ld_wt(const float* p) {
  return __hip_atomic_load(p, __ATOMIC_RELAXED, __HIP_MEMORY_SCOPE_AGENT);
}

// Split arrive/wait 64-block barrier. Callers guarantee a __syncthreads()
// (which drains each thread's vmcnt) precedes arrive, so all of this block's
// write-through stores have reached the coherence point before the flag bump.
__device__ __forceinline__ void bar_arrive(unsigned* cnt, unsigned* gen) {
  unsigned old = __hip_atomic_fetch_add(cnt, 1u, __ATOMIC_RELAXED, __HIP_MEMORY_SCOPE_AGENT);
  if (old == GB_ - 1u) {
    __hip_atomic_store(cnt, 0u, __ATOMIC_RELAXED, __HIP_MEMORY_SCOPE_AGENT);
    asm volatile("s_waitcnt vmcnt(0)" ::: "memory");  // reset visible before gen bump
    __hip_atomic_fetch_add(gen, 1u, __ATOMIC_RELAXED, __HIP_MEMORY_SCOPE_AGENT);
  }
}
__device__ __forceinline__ int bar_wait(unsigned* gen, unsigned target, unsigned* abrt) {
  long spins = 0;
  for (;;) {
    unsigned g = __hip_atomic_load(gen, __ATOMIC_RELAXED, __HIP_MEMORY_SCOPE_AGENT);
    if ((int)(g - target) >= 0) return 0;
    if (((++spins) & 255) == 0) {
      if (__hip_atomic_load(abrt, __ATOMIC_RELAXED, __HIP_MEMORY_SCOPE_AGENT)) return 1;
      if (spins > 6000000L) {
        __hip_atomic_store(abrt, 1u, __ATOMIC_RELAXED, __HIP_MEMORY_SCOPE_AGENT);
        return 1;
      }
    }
    __builtin_amdgcn_s_sleep(1);
  }
}

// ---------------------------------------------------------------------------
// Persistent recurrent kernel. 256 blocks x 256 threads, 1 block/CU.
// Sync groups of 64 blocks are dependency-closed: block g's G-role serves
// batch-group g>>6; its U-role batch g>>3 lies in the same group.
// Cross-block data (gates, h in out) moves via write-through atomics only —
// no threadfence / L2 writeback anywhere.
// ---------------------------------------------------------------------------
__global__ __launch_bounds__(256, 1) void recurrent_k(
    const float* __restrict__ v_buf,   // [B][T][I]
    const float* __restrict__ alpha,   // [B][T][T]
    const float* __restrict__ W_ih,    // [4H][I]
    const float* __restrict__ W_hh,    // [4H][H]
    const float* __restrict__ b_ih, const float* __restrict__ b_hh,
    float* gates,                      // [B][4H] scratch (coherent traffic)
    float* out,                        // [B][T][H] = h_n (also h state)
    unsigned* bar)
{
  extern __shared__ float lds[];
  float* hv  = lds;                    // [8][640]  staged [v | h_prev]
  float* cn  = lds + 8 * 640;          // [512][64] cell history
  float* red = cn + 512 * 64;          // [256]
  __shared__ int s_ab;

  const int tid = threadIdx.x;
  const int g = blockIdx.x;
  const int grp = g >> 6;
  const int rs = g & 63, bg = grp;          // G role
  const int b_u = g >> 3, hs = g & 7;       // U role
  const int r_l = tid >> 3, cg = tid & 7;   // G thread
  const int row = rs * 32 + r_l;
  const int jg = tid >> 6, l = tid & 63;    // U thread

  unsigned* cntA = bar + grp * 128 + 0;     // 128B-line-separated
  unsigned* genA = bar + grp * 128 + 32;
  unsigned* cntB = bar + grp * 128 + 64;
  unsigned* genB = bar + grp * 128 + 96;
  unsigned* abrt = bar + 1023;

  // stationary weights: cols c = cg*4 + k*32 of [W_ih | W_hh] row
  float4 wreg[20];
  #pragma unroll
  for (int k = 0; k < 20; ++k) {
    int c0 = cg * 4 + k * 32;
    if (k < 4) wreg[k] = *(const float4*)&W_ih[(long)row * I_ + c0];
    else       wreg[k] = *(const float4*)&W_hh[(long)row * H_ + (c0 - 128)];
  }
  const float bias = b_ih[row] + b_hh[row];

  for (int t = 0; t < T_; ++t) {
    // ---- wait: h(t-1) ready (genA == t; trivially true at t=0) ----
    if (tid == 0) s_ab = bar_wait(genA, (unsigned)t, abrt);
    __syncthreads();
    if (s_ab) return;

    // ---- stage hv = [v(b,t,:) | h(b,t-1,:)] for the 8 G-batches ----
    {
      int bp = tid >> 5, c4 = (tid & 31) << 2;
      float4 vv = *(const float4*)&v_buf[((long)(bg * 8 + bp) * T_ + t) * I_ + c4];
      *(float4*)&hv[bp * 640 + c4] = vv;
    }
    if (t > 0) {
      #pragma unroll
      for (int s = 0; s < 16; ++s) {
        int idx = tid + s * 256;
        int bp = idx >> 9, c = idx & 511;
        hv[bp * 640 + 128 + c] = ld_wt(&out[((long)(bg * 8 + bp) * T_ + (t - 1)) * H_ + c]);
      }
    } else {
      #pragma unroll
      for (int s = 0; s < 16; ++s) {
        int idx = tid + s * 256;
        int bp = idx >> 9, c = idx & 511;
        hv[bp * 640 + 128 + c] = 0.f;
      }
    }
    __syncthreads();

    // ---- G: gates partial dot over this cg's 80 columns, 8 batches ----
    float acc[8] = {};
    #pragma unroll
    for (int k = 0; k < 20; ++k) {
      float4 w4 = wreg[k];
      #pragma unroll
      for (int bp = 0; bp < 8; ++bp) {
        float4 x = *(const float4*)&hv[bp * 640 + cg * 4 + k * 32];
        acc[bp] += w4.x * x.x + w4.y * x.y + w4.z * x.z + w4.w * x.w;
      }
    }
    #pragma unroll
    for (int off = 1; off < 8; off <<= 1) {
      #pragma unroll
      for (int bp = 0; bp < 8; ++bp) acc[bp] += __shfl_xor(acc[bp], off);
    }
    if (cg == 0) {
      #pragma unroll
      for (int bp = 0; bp < 8; ++bp)
        st_wt(&gates[(long)(bg * 8 + bp) * G4_ + row], acc[bp] + bias);
    }
    __syncthreads();                       // drains every thread's gate stores
    if (tid == 0) bar_arrive(cntB, genB);  // signal gates early

    // ---- C partial: independent of gates — overlaps the gates wait ----
    float partial = 0.f;
    {
      const float* arow = alpha + ((long)b_u * T_ + t) * T_;
      int j0 = jg * 128, j1 = j0 + 128; if (j1 > t) j1 = t;
      for (int j = j0; j < j1; ++j)
        partial += arow[j] * cn[j * 64 + l];
    }
    red[tid] = partial;
    if (tid == 0) s_ab = bar_wait(genB, (unsigned)(t + 1), abrt);
    __syncthreads();                       // red[] visible + s_ab broadcast
    if (s_ab) return;

    // ---- U finish: gates -> (i,f,g,o), cell/hidden update ----
    if (tid < 64) {
      const long gb = (long)b_u * G4_ + hs * 64 + l;
      float gi = ld_wt(&gates[gb]);
      float gf = ld_wt(&gates[gb + H_]);
      float gg = ld_wt(&gates[gb + 2 * H_]);
      float go = ld_wt(&gates[gb + 3 * H_]);
      float C  = red[l] + red[64 + l] + red[128 + l] + red[192 + l];
      float si = 1.f / (1.f + expf(-gi));
      float sf = 1.f / (1.f + expf(-gf));
      float so = 1.f / (1.f + expf(-go));
      float cnew = sf * C + si * tanhf(gg);
      float hnew = so * tanhf(cnew);
      st_wt(&out[((long)b_u * T_ + t) * H_ + hs * 64 + l], hnew);
      cn[t * 64 + l] = cnew;
    }
    __syncthreads();                       // drains h stores
    if (tid == 0) bar_arrive(cntA, genA);  // h(t) ready
  }
}

// ---------------------------------------------------------------------------
extern "C" void kernel_launch(void* const* d_in, const int* in_sizes, int n_in,
                              void* d_out, int out_size, void* d_ws, size_t ws_size,
                              hipStream_t stream)
{
  const float* values  = (const float*)d_in[0];
  const float* Deltas  = (const float*)d_in[1];
  // d_in[2] = ys (unused by the reference computation)
  const float* W_ih    = (const float*)d_in[3];
  const float* W_hh    = (const float*)d_in[4];
  const float* b_ih    = (const float*)d_in[5];
  const float* b_hh    = (const float*)d_in[6];
  const float* atten_W = (const float*)d_in[7];
  const float* atten_b = (const float*)d_in[8];
  float* out = (float*)d_out;

  char* ws = (char*)d_ws;
  unsigned* bar = (unsigned*)ws;                       // 4 KB (flags)
  float* v_buf  = (float*)(ws + 4096);                 // 8 MB   [B][T][I]
  float* a_buf  = (float*)(ws + 4096 + 8388608);       // 32 MB  [B][T][T]
  float* dcum   = (float*)(ws + 4096 + 8388608 + 33554432);            // 64 KB
  float* gates  = (float*)(ws + 4096 + 8388608 + 33554432 + 65536);    // 256 KB

  hipMemsetAsync(bar, 0, 4096, stream);

  // v = values @ atten_W^T + atten_b   (M=B*T=16384, N=128, K=128)
  gemm_abt<<<dim3(256, 2, 1), 256, 0, stream>>>(values, atten_W, v_buf, atten_b,
                                                0, 0, 0, 128);
  cumsum_k<<<32, 512, 0, stream>>>(Deltas, dcum);
  // a[b,t,j] = v[b,t,:] . values[b,j,:]   (per-batch 512x512x128)
  gemm_abt<<<dim3(8, 8, 32), 256, 0, stream>>>(v_buf, values, a_buf, nullptr,
                                               512L * 128, 512L * 128, 512L * 512, 512);
  softmax_k<<<dim3(512, 32), 64, 0, stream>>>(a_buf, dcum);

  (void)hipFuncSetAttribute((const void*)recurrent_k,
                            hipFuncAttributeMaxDynamicSharedMemorySize, 152576);
  recurrent_k<<<256, 256, 152576, stream>>>(v_buf, a_buf, W_ih, W_hh, b_ih, b_hh,
                                            gates, out, bar);
}